// Round 6
// baseline (634.897 us; speedup 1.0000x reference)
//
#include <hip/hip_runtime.h>

// ---------------------------------------------------------------------------
// B=4, N=1024 (32x32), DIM=512, HEADS=8, DH=64.
// Outputs: out [4,1024,512] fp32, then softmax(dots0) [4,8,1024,1024] fp32.
// ---------------------------------------------------------------------------

__device__ __forceinline__ float wsum(float v) {
#pragma unroll
  for (int off = 32; off > 0; off >>= 1) v += __shfl_xor(v, off, 64);
  return v;
}
__device__ __forceinline__ float wmaxr(float v) {
#pragma unroll
  for (int off = 32; off > 0; off >>= 1) v = fmaxf(v, __shfl_xor(v, off, 64));
  return v;
}
__device__ __forceinline__ float wminr(float v) {
#pragma unroll
  for (int off = 32; off > 0; off >>= 1) v = fminf(v, __shfl_xor(v, off, 64));
  return v;
}

// ---------------------------------------------------------------------------
// K0: combined bias table btab[h][(dy+31)*63+(dx+31)] = rpb[idx][h]
//     + 0.01*exp(-factor_h*((dy/32)^2+(dx/32)^2)).
// ---------------------------------------------------------------------------
__global__ void build_btab(const float* __restrict__ rpb,
                           const float* __restrict__ headsita,
                           float* __restrict__ btab) {
  const int h = blockIdx.y;
  const int flat = blockIdx.x * 256 + threadIdx.x;
  if (flat >= 3969) return;
  const float sita = headsita[h];
  const float factor = 1.0f / (2.0f * sita * sita + 1e-6f);
  const int dy = flat / 63 - 31;
  const int dx = flat % 63 - 31;
  const float fy = (float)dy * 0.03125f, fx = (float)dx * 0.03125f;
  btab[h * 3969 + flat] =
      rpb[(size_t)flat * 8 + h] + 0.01f * __expf(-factor * (fy * fy + fx * fx));
}

// ---------------------------------------------------------------------------
// K1: C[M,N] = A[M,K] @ B[K,N]; 128x128 tile, 8x8 microtile (r3 exact).
// ---------------------------------------------------------------------------
__global__ __launch_bounds__(256) void gemm_f32_128(
    const float* __restrict__ A, const float* __restrict__ Bm,
    float* __restrict__ C, int M, int N, int K) {
  __shared__ float As[16][132];
  __shared__ float Bs[16][132];
  const int t = threadIdx.x;
  const int bm = blockIdx.y * 128;
  const int bn = blockIdx.x * 128;
  const int tx = t & 15;
  const int ty = t >> 4;

  float acc[8][8];
#pragma unroll
  for (int i = 0; i < 8; ++i)
#pragma unroll
    for (int j = 0; j < 8; ++j) acc[i][j] = 0.0f;

  const int mr = t >> 1;
  const int kc = (t & 1) * 8;
  const int kr = t >> 4;
  const int nc = (t & 15) * 8;

  for (int k0 = 0; k0 < K; k0 += 16) {
    const float4* asrc = (const float4*)&A[(size_t)(bm + mr) * K + k0 + kc];
    const float4 a0 = asrc[0], a1 = asrc[1];
    const float4* bsrc = (const float4*)&Bm[(size_t)(k0 + kr) * N + bn + nc];
    const float4 b0 = bsrc[0], b1 = bsrc[1];
    __syncthreads();
    As[kc + 0][mr] = a0.x; As[kc + 1][mr] = a0.y;
    As[kc + 2][mr] = a0.z; As[kc + 3][mr] = a0.w;
    As[kc + 4][mr] = a1.x; As[kc + 5][mr] = a1.y;
    As[kc + 6][mr] = a1.z; As[kc + 7][mr] = a1.w;
    *(float4*)&Bs[kr][nc] = b0;
    *(float4*)&Bs[kr][nc + 4] = b1;
    __syncthreads();
#pragma unroll
    for (int kk = 0; kk < 16; ++kk) {
      const float4 aLo = *(const float4*)&As[kk][ty * 4];
      const float4 aHi = *(const float4*)&As[kk][64 + ty * 4];
      const float4 bLo = *(const float4*)&Bs[kk][tx * 4];
      const float4 bHi = *(const float4*)&Bs[kk][64 + tx * 4];
      const float av[8] = {aLo.x, aLo.y, aLo.z, aLo.w, aHi.x, aHi.y, aHi.z, aHi.w};
      const float bv[8] = {bLo.x, bLo.y, bLo.z, bLo.w, bHi.x, bHi.y, bHi.z, bHi.w};
#pragma unroll
      for (int i = 0; i < 8; ++i)
#pragma unroll
        for (int j = 0; j < 8; ++j) acc[i][j] += av[i] * bv[j];
    }
  }

#pragma unroll
  for (int i = 0; i < 8; ++i) {
    const int row = bm + ((i < 4) ? (ty * 4 + i) : (64 + ty * 4 + (i - 4)));
    float4 lo, hi;
    lo.x = acc[i][0]; lo.y = acc[i][1]; lo.z = acc[i][2]; lo.w = acc[i][3];
    hi.x = acc[i][4]; hi.y = acc[i][5]; hi.z = acc[i][6]; hi.w = acc[i][7];
    *(float4*)&C[(size_t)row * N + bn + tx * 4] = lo;
    *(float4*)&C[(size_t)row * N + bn + 64 + tx * 4] = hi;
  }
}

// ---------------------------------------------------------------------------
// K2: fused attention v6. Grid (32,32) XCD-remapped; block 256 = 4 waves x 8
// query rows. Score row s[8][16] kept in REGISTERS (launch_bounds(256,2) so
// the allocator has 256 VGPRs -> no scratch spill; r3-r5 spilled ~134MB).
// QK^T: K staged [256][32] with granule swizzle g=(d>>2)^(row&7) -> b128
//   reads, 8 bank-groups x 8 lanes (optimal); q [row][72] -> b128 broadcast,
//   256-col j-tiles x 2 d-halves amortize q reads.
// PV: p stays in registers; readlane broadcasts p[r][col] to SGPR; V tile
//   plain [64][64] (row-broadcast b32 reads are conflict-free).
// ---------------------------------------------------------------------------
__global__ __launch_bounds__(256, 2) void attn_fused(
    const float* __restrict__ qkv,       // [4,1024,1536]
    const float* __restrict__ prob,      // [4,1024]
    const float* __restrict__ btab,      // [8,3969]
    const float* __restrict__ w_thresh,  // [64]
    float* __restrict__ out2,            // [4,8,1024,1024]
    float* __restrict__ attnout)         // [4,1024,512]
{
  __shared__ float kv[8192];       // 32KB: K [256][32] swz | V [64][64] plain
  __shared__ float qrow[32 * 72];  // 9.2KB: q [row][72] (288B rows, 16B-aligned)
  __shared__ float bt[2016];       // 8.1KB: combined bias slice

  const int t = threadIdx.x;
  const int w = t >> 6, l = t & 63;
  const int id = blockIdx.y * 32 + blockIdx.x;
  const int work = (id & 7) * 128 + (id >> 3);  // XCD-aware bijective remap
  const int bh = work >> 5;
  const int itile = work & 31;
  const int b = bh >> 3, h = bh & 7;
  const int i0 = itile * 32;

  // stage combined-bias slice (contiguous)
  const float* bsl = btab + h * 3969 + itile * 63;
#pragma unroll
  for (int c = 0; c < 8; ++c) {
    const int e = c * 256 + t;
    if (e < 2016) bt[e] = bsl[e];
  }
  // stage q rows: qrow[row][d], row-major pad 72
#pragma unroll
  for (int c = 0; c < 8; ++c) {
    const int idx = c * 256 + t;
    const int row = idx >> 6, d = idx & 63;
    qrow[row * 72 + d] = qkv[(size_t)(b * 1024 + i0 + row) * 1536 + h * 64 + d];
  }
  __syncthreads();

  // per-row threshold; prob row-mask folded in (+2 -> threshold unreachable)
  const float wt = w_thresh[l];
  float tval[8];
#pragma unroll
  for (int r = 0; r < 8; ++r) {
    const int row = w * 8 + r;
    const float v = wsum(qrow[row * 72 + l] * wt);
    float tv = (1.0f / (1.0f + __expf(-v))) * 0.11920292202211755f;
    tv += (prob[b * 1024 + i0 + row] >= 0.9f) ? 2.0f : 0.0f;
    tval[r] = tv;
  }

  float s[8][16];
#pragma unroll
  for (int r = 0; r < 8; ++r)
#pragma unroll
    for (int tt = 0; tt < 16; ++tt) s[r][tt] = 0.0f;

  // ---- QK^T: 4 tiles of 256 cols x 2 d-halves; K [256][32] swizzled ----
  const size_t kbase = (size_t)b * 1024 * 1536 + 512 + h * 64;
  const int l7 = l & 7;
#pragma unroll
  for (int jt = 0; jt < 4; ++jt) {
    for (int dh = 0; dh < 2; ++dh) {
      __syncthreads();
#pragma unroll
      for (int c = 0; c < 8; ++c) {  // stage 256 rows x 32 d
        const int q = c * 256 + t;
        const int j = q >> 3;             // 0..255
        const int dd = (q & 7) * 4;       // 0..28
        const float4 va = *(const float4*)&qkv[kbase + (size_t)(jt * 256 + j) * 1536 + dh * 32 + dd];
        *(float4*)&kv[j * 32 + 4 * ((dd >> 2) ^ (j & 7))] = va;
      }
      __syncthreads();
      for (int d0 = 0; d0 < 32; d0 += 4) {
        const int g = 4 * ((d0 >> 2) ^ l7);
        const float4 k0 = *(const float4*)&kv[l * 32 + g];
        const float4 k1 = *(const float4*)&kv[(64 + l) * 32 + g];
        const float4 k2 = *(const float4*)&kv[(128 + l) * 32 + g];
        const float4 k3 = *(const float4*)&kv[(192 + l) * 32 + g];
#pragma unroll
        for (int r = 0; r < 8; ++r) {
          const float4 q4 = *(const float4*)&qrow[(w * 8 + r) * 72 + dh * 32 + d0];
          s[r][jt * 4 + 0] = fmaf(q4.w, k0.w, fmaf(q4.z, k0.z, fmaf(q4.y, k0.y, fmaf(q4.x, k0.x, s[r][jt * 4 + 0]))));
          s[r][jt * 4 + 1] = fmaf(q4.w, k1.w, fmaf(q4.z, k1.z, fmaf(q4.y, k1.y, fmaf(q4.x, k1.x, s[r][jt * 4 + 1]))));
          s[r][jt * 4 + 2] = fmaf(q4.w, k2.w, fmaf(q4.z, k2.z, fmaf(q4.y, k2.y, fmaf(q4.x, k2.x, s[r][jt * 4 + 2]))));
          s[r][jt * 4 + 3] = fmaf(q4.w, k3.w, fmaf(q4.z, k3.z, fmaf(q4.y, k3.y, fmaf(q4.x, k3.x, s[r][jt * 4 + 3]))));
        }
      }
    }
  }
  // column owned by lane l at slot tt: j = tt_quarter... global col = jt*256 + u*64 + l,
  // i.e. slot tt = jt*4+u holds col tt*64 + l  (since jt*256+u*64 = (jt*4+u)*64).

  // ---- scale + softmax(dots0) -> out2 (nontemporal streaming) ----
  const size_t o2base = ((size_t)(b * 8 + h)) << 20;
#pragma unroll
  for (int r = 0; r < 8; ++r) {
#pragma unroll
    for (int tt = 0; tt < 16; ++tt) s[r][tt] *= 0.125f;
    float m = -1e30f;
#pragma unroll
    for (int tt = 0; tt < 16; ++tt) m = fmaxf(m, s[r][tt]);
    m = wmaxr(m);
    float sum = 0.0f;
#pragma unroll
    for (int tt = 0; tt < 16; ++tt) sum += __expf(s[r][tt] - m);
    sum = wsum(sum);
    const float inv = 1.0f / sum;
    float* orow = out2 + o2base + (size_t)(i0 + w * 8 + r) * 1024;
#pragma unroll
    for (int tt = 0; tt < 16; ++tt)
      __builtin_nontemporal_store(__expf(s[r][tt] - m) * inv, &orow[tt * 64 + l]);
  }

  // ---- add combined RPE bias ----
#pragma unroll
  for (int r = 0; r < 8; ++r) {
    const int xi = w * 8 + r;  // (i0+row)&31 == row since i0 % 32 == 0
#pragma unroll
    for (int tt = 0; tt < 16; ++tt) {
      const int j = tt * 64 + l;
      const int yj = j >> 5, xj = j & 31;
      s[r][tt] += bt[(31 - yj) * 63 + (xi - xj + 31)];
    }
  }

  // ---- softmax(dots) + threshold prune + renorm (e-space) ----
#pragma unroll
  for (int r = 0; r < 8; ++r) {
    float m = -1e30f, mn = 1e30f;
#pragma unroll
    for (int tt = 0; tt < 16; ++tt) { m = fmaxf(m, s[r][tt]); mn = fminf(mn, s[r][tt]); }
    m = wmaxr(m); mn = wminr(mn);
    float sum = 0.0f;
#pragma unroll
    for (int tt = 0; tt < 16; ++tt) { const float e = __expf(s[r][tt] - m); s[r][tt] = e; sum += e; }
    sum = wsum(sum);
    const float emin = __expf(mn - m);
    const float th_e = emin + tval[r] * (1.0f - emin);  // attn>th <=> e>th_e
    float deno = 0.0f;
#pragma unroll
    for (int tt = 0; tt < 16; ++tt) {
      const float a = (s[r][tt] > th_e) ? s[r][tt] : 0.0f;
      s[r][tt] = a;
      deno += a;
    }
    deno = wsum(deno);
    const float invden = 1.0f / (deno + 1e-6f * sum);
#pragma unroll
    for (int tt = 0; tt < 16; ++tt) s[r][tt] *= invden;
  }

  // ---- PV: 16 V-tiles of 64 rows, plain [64][64]; p via readlane ----
  float outv[8];
#pragma unroll
  for (int r = 0; r < 8; ++r) outv[r] = 0.0f;
  const size_t vbase = (size_t)b * 1024 * 1536 + 1024 + h * 64;
#pragma unroll
  for (int tt = 0; tt < 16; ++tt) {
    __syncthreads();
#pragma unroll
    for (int c = 0; c < 4; ++c) {  // stage 64 rows x 64 d
      const int f = (c * 256 + t) * 4;
      const int j = f >> 6, dd = f & 63;
      *(float4*)&kv[j * 64 + dd] =
          *(const float4*)&qkv[vbase + (size_t)(tt * 64 + j) * 1536 + dd];
    }
    __syncthreads();
#pragma unroll 4
    for (int jl = 0; jl < 64; ++jl) {
      const float vv = kv[jl * 64 + l];  // row broadcast, conflict-free
#pragma unroll
      for (int r = 0; r < 8; ++r) {
        const float pv = __int_as_float(
            __builtin_amdgcn_readlane(__float_as_int(s[r][tt]), jl));
        outv[r] = fmaf(pv, vv, outv[r]);
      }
    }
  }
#pragma unroll
  for (int r = 0; r < 8; ++r)
    attnout[(size_t)(b * 1024 + i0 + w * 8 + r) * 512 + h * 64 + l] = outv[r];
}

// ---------------------------------------------------------------------------
// K3: C = A @ B + bias; 64x64 tile, 4x4 microtile (r3 exact).
// ---------------------------------------------------------------------------
__global__ __launch_bounds__(256) void gemm_f32_64_bias(
    const float* __restrict__ A, const float* __restrict__ Bm,
    const float* __restrict__ bias, float* __restrict__ C,
    int M, int N, int K) {
  __shared__ float As[16][68];
  __shared__ float Bs[16][68];
  const int t = threadIdx.x;
  const int bm = blockIdx.y * 64;
  const int bn = blockIdx.x * 64;
  const int tx = t & 15;
  const int ty = t >> 4;

  float acc[4][4];
#pragma unroll
  for (int i = 0; i < 4; ++i)
#pragma unroll
    for (int j = 0; j < 4; ++j) acc[i][j] = 0.0f;

  const int amr = t >> 2;
  const int akc = (t & 3) * 4;
  const int bkr = t >> 4;
  const int bnc = (t & 15) * 4;

  for (int k0 = 0; k0 < K; k0 += 16) {
    const float4 a0 = *(const float4*)&A[(size_t)(bm + amr) * K + k0 + akc];
    const float4 b0 = *(const float4*)&Bm[(size_t)(k0 + bkr) * N + bn + bnc];
    __syncthreads();
    As[akc + 0][amr] = a0.x; As[akc + 1][amr] = a0.y;
    As[akc + 2][amr] = a0.z; As[akc + 3][amr] = a0.w;
    *(float4*)&Bs[bkr][bnc] = b0;
    __syncthreads();
#pragma unroll
    for (int kk = 0; kk < 16; ++kk) {
      const float4 av = *(const float4*)&As[kk][ty * 4];
      const float4 bv = *(const float4*)&Bs[kk][tx * 4];
      const float aa[4] = {av.x, av.y, av.z, av.w};
      const float bb[4] = {bv.x, bv.y, bv.z, bv.w};
#pragma unroll
      for (int i = 0; i < 4; ++i)
#pragma unroll
        for (int j = 0; j < 4; ++j) acc[i][j] += aa[i] * bb[j];
    }
  }

  const float4 bi = *(const float4*)&bias[bn + tx * 4];
#pragma unroll
  for (int i = 0; i < 4; ++i) {
    float4 o;
    o.x = acc[i][0] + bi.x; o.y = acc[i][1] + bi.y;
    o.z = acc[i][2] + bi.z; o.w = acc[i][3] + bi.w;
    *(float4*)&C[(size_t)(bm + ty * 4 + i) * N + bn + tx * 4] = o;
  }
}

// ---------------------------------------------------------------------------
extern "C" void kernel_launch(void* const* d_in, const int* in_sizes, int n_in,
                              void* d_out, int out_size, void* d_ws, size_t ws_size,
                              hipStream_t stream) {
  const float* x        = (const float*)d_in[0];  // [4,1024,512]
  const float* prob     = (const float*)d_in[1];  // [4,1024]
  const float* w_qkv    = (const float*)d_in[2];  // [512,1536]
  const float* rpb      = (const float*)d_in[3];  // [3969,8]
  const float* headsita = (const float*)d_in[4];  // [8]
  const float* w_thresh = (const float*)d_in[5];  // [64]
  const float* w_out    = (const float*)d_in[6];  // [512,512]
  const float* b_out    = (const float*)d_in[7];  // [512]
  // d_in[8] = rpi, d_in[9] = dis : recomputed analytically.

  float* out  = (float*)d_out;                    // [4,1024,512]
  float* out2 = out + (size_t)4 * 1024 * 512;     // [4,8,1024,1024]

  float* qkv     = (float*)d_ws;                      // 6.29M floats
  float* attnout = qkv + (size_t)4 * 1024 * 1536;     // 2.1M floats
  float* btab    = attnout + (size_t)4 * 1024 * 512;  // 8*3969 floats

  // 0) combined bias table
  build_btab<<<dim3(16, 8), 256, 0, stream>>>(rpb, headsita, btab);

  // 1) QKV projection: [4096,512] @ [512,1536]
  gemm_f32_128<<<dim3(1536 / 128, 4096 / 128), 256, 0, stream>>>(
      x, w_qkv, qkv, 4096, 1536, 512);

  // 2) fused attention
  attn_fused<<<dim3(32, 32), 256, 0, stream>>>(
      qkv, prob, btab, w_thresh, out2, attnout);

  // 3) output projection + bias: [4096,512] @ [512,512]
  gemm_f32_64_bias<<<dim3(512 / 64, 4096 / 64), 256, 0, stream>>>(
      attnout, w_out, b_out, out, 4096, 512, 512);
}

// Round 7
// 598.253 us; speedup vs baseline: 1.0613x; 1.0613x over previous
//
#include <hip/hip_runtime.h>

// ---------------------------------------------------------------------------
// B=4, N=1024 (32x32), DIM=512, HEADS=8, DH=64.
// Outputs: out [4,1024,512] fp32, then softmax(dots0) [4,8,1024,1024] fp32.
// ---------------------------------------------------------------------------

__device__ __forceinline__ float wsum(float v) {
#pragma unroll
  for (int off = 32; off > 0; off >>= 1) v += __shfl_xor(v, off, 64);
  return v;
}
__device__ __forceinline__ float wmaxr(float v) {
#pragma unroll
  for (int off = 32; off > 0; off >>= 1) v = fmaxf(v, __shfl_xor(v, off, 64));
  return v;
}
__device__ __forceinline__ float wminr(float v) {
#pragma unroll
  for (int off = 32; off > 0; off >>= 1) v = fminf(v, __shfl_xor(v, off, 64));
  return v;
}

// ---------------------------------------------------------------------------
// K0: combined bias table btab[h][(dy+31)*63+(dx+31)] = rpb[idx][h]
//     + 0.01*exp(-factor_h*((dy/32)^2+(dx/32)^2)).
// ---------------------------------------------------------------------------
__global__ void build_btab(const float* __restrict__ rpb,
                           const float* __restrict__ headsita,
                           float* __restrict__ btab) {
  const int h = blockIdx.y;
  const int flat = blockIdx.x * 256 + threadIdx.x;
  if (flat >= 3969) return;
  const float sita = headsita[h];
  const float factor = 1.0f / (2.0f * sita * sita + 1e-6f);
  const int dy = flat / 63 - 31;
  const int dx = flat % 63 - 31;
  const float fy = (float)dy * 0.03125f, fx = (float)dx * 0.03125f;
  btab[h * 3969 + flat] =
      rpb[(size_t)flat * 8 + h] + 0.01f * __expf(-factor * (fy * fy + fx * fx));
}

// ---------------------------------------------------------------------------
// K1: C[M,N] = A[M,K] @ B[K,N]; 128x128 tile, 8x8 microtile (r3 exact).
// ---------------------------------------------------------------------------
__global__ __launch_bounds__(256) void gemm_f32_128(
    const float* __restrict__ A, const float* __restrict__ Bm,
    float* __restrict__ C, int M, int N, int K) {
  __shared__ float As[16][132];
  __shared__ float Bs[16][132];
  const int t = threadIdx.x;
  const int bm = blockIdx.y * 128;
  const int bn = blockIdx.x * 128;
  const int tx = t & 15;
  const int ty = t >> 4;

  float acc[8][8];
#pragma unroll
  for (int i = 0; i < 8; ++i)
#pragma unroll
    for (int j = 0; j < 8; ++j) acc[i][j] = 0.0f;

  const int mr = t >> 1;
  const int kc = (t & 1) * 8;
  const int kr = t >> 4;
  const int nc = (t & 15) * 8;

  for (int k0 = 0; k0 < K; k0 += 16) {
    const float4* asrc = (const float4*)&A[(size_t)(bm + mr) * K + k0 + kc];
    const float4 a0 = asrc[0], a1 = asrc[1];
    const float4* bsrc = (const float4*)&Bm[(size_t)(k0 + kr) * N + bn + nc];
    const float4 b0 = bsrc[0], b1 = bsrc[1];
    __syncthreads();
    As[kc + 0][mr] = a0.x; As[kc + 1][mr] = a0.y;
    As[kc + 2][mr] = a0.z; As[kc + 3][mr] = a0.w;
    As[kc + 4][mr] = a1.x; As[kc + 5][mr] = a1.y;
    As[kc + 6][mr] = a1.z; As[kc + 7][mr] = a1.w;
    *(float4*)&Bs[kr][nc] = b0;
    *(float4*)&Bs[kr][nc + 4] = b1;
    __syncthreads();
#pragma unroll
    for (int kk = 0; kk < 16; ++kk) {
      const float4 aLo = *(const float4*)&As[kk][ty * 4];
      const float4 aHi = *(const float4*)&As[kk][64 + ty * 4];
      const float4 bLo = *(const float4*)&Bs[kk][tx * 4];
      const float4 bHi = *(const float4*)&Bs[kk][64 + tx * 4];
      const float av[8] = {aLo.x, aLo.y, aLo.z, aLo.w, aHi.x, aHi.y, aHi.z, aHi.w};
      const float bv[8] = {bLo.x, bLo.y, bLo.z, bLo.w, bHi.x, bHi.y, bHi.z, bHi.w};
#pragma unroll
      for (int i = 0; i < 8; ++i)
#pragma unroll
        for (int j = 0; j < 8; ++j) acc[i][j] += av[i] * bv[j];
    }
  }

#pragma unroll
  for (int i = 0; i < 8; ++i) {
    const int row = bm + ((i < 4) ? (ty * 4 + i) : (64 + ty * 4 + (i - 4)));
    float4 lo, hi;
    lo.x = acc[i][0]; lo.y = acc[i][1]; lo.z = acc[i][2]; lo.w = acc[i][3];
    hi.x = acc[i][4]; hi.y = acc[i][5]; hi.z = acc[i][6]; hi.w = acc[i][7];
    *(float4*)&C[(size_t)row * N + bn + tx * 4] = lo;
    *(float4*)&C[(size_t)row * N + bn + 64 + tx * 4] = hi;
  }
}

// ---------------------------------------------------------------------------
// K2: fused attention v7 == v6 structure, ONE change: amdgpu_waves_per_eu(2,2)
// pins the allocator to a 256-VGPR budget (empirically launch_bounds' arg2
// was treated as target/2 -> 128 VGPR -> s[8][16] spilled ~124MB to scratch;
// r3-r6 were scratch-bandwidth-bound, not LDS/VALU-bound).
// QK^T: K staged [256][32], granule swizzle (d>>2)^(row&7) -> b128 reads;
//   q [row][72] b128 broadcasts; 4 col-tiles x 2 d-halves.
// PV: p in regs, readlane broadcast; V plain [64][64] row-broadcast reads.
// ---------------------------------------------------------------------------
__global__ __launch_bounds__(256)
__attribute__((amdgpu_waves_per_eu(2, 2)))
void attn_fused(
    const float* __restrict__ qkv,       // [4,1024,1536]
    const float* __restrict__ prob,      // [4,1024]
    const float* __restrict__ btab,      // [8,3969]
    const float* __restrict__ w_thresh,  // [64]
    float* __restrict__ out2,            // [4,8,1024,1024]
    float* __restrict__ attnout)         // [4,1024,512]
{
  __shared__ float kv[8192];       // 32KB: K [256][32] swz | V [64][64] plain
  __shared__ float qrow[32 * 72];  // 9.2KB: q [row][72]
  __shared__ float bt[2016];       // 8.1KB: combined bias slice

  const int t = threadIdx.x;
  const int w = t >> 6, l = t & 63;
  const int id = blockIdx.y * 32 + blockIdx.x;
  const int work = (id & 7) * 128 + (id >> 3);  // XCD-aware bijective remap
  const int bh = work >> 5;
  const int itile = work & 31;
  const int b = bh >> 3, h = bh & 7;
  const int i0 = itile * 32;

  // stage combined-bias slice (contiguous)
  const float* bsl = btab + h * 3969 + itile * 63;
#pragma unroll
  for (int c = 0; c < 8; ++c) {
    const int e = c * 256 + t;
    if (e < 2016) bt[e] = bsl[e];
  }
  // stage q rows: qrow[row][d]
#pragma unroll
  for (int c = 0; c < 8; ++c) {
    const int idx = c * 256 + t;
    const int row = idx >> 6, d = idx & 63;
    qrow[row * 72 + d] = qkv[(size_t)(b * 1024 + i0 + row) * 1536 + h * 64 + d];
  }
  __syncthreads();

  // per-row threshold; prob row-mask folded in (+2 -> threshold unreachable)
  const float wt = w_thresh[l];
  float tval[8];
#pragma unroll
  for (int r = 0; r < 8; ++r) {
    const int row = w * 8 + r;
    const float v = wsum(qrow[row * 72 + l] * wt);
    float tv = (1.0f / (1.0f + __expf(-v))) * 0.11920292202211755f;
    tv += (prob[b * 1024 + i0 + row] >= 0.9f) ? 2.0f : 0.0f;
    tval[r] = tv;
  }

  float s[8][16];
#pragma unroll
  for (int r = 0; r < 8; ++r)
#pragma unroll
    for (int tt = 0; tt < 16; ++tt) s[r][tt] = 0.0f;

  // ---- QK^T: 4 tiles of 256 cols x 2 d-halves; K [256][32] swizzled ----
  const size_t kbase = (size_t)b * 1024 * 1536 + 512 + h * 64;
  const int l7 = l & 7;
#pragma unroll
  for (int jt = 0; jt < 4; ++jt) {
    for (int dh = 0; dh < 2; ++dh) {
      __syncthreads();
#pragma unroll
      for (int c = 0; c < 8; ++c) {  // stage 256 rows x 32 d
        const int q = c * 256 + t;
        const int j = q >> 3;             // 0..255
        const int dd = (q & 7) * 4;       // 0..28
        const float4 va = *(const float4*)&qkv[kbase + (size_t)(jt * 256 + j) * 1536 + dh * 32 + dd];
        *(float4*)&kv[j * 32 + 4 * ((dd >> 2) ^ (j & 7))] = va;
      }
      __syncthreads();
      for (int d0 = 0; d0 < 32; d0 += 4) {
        const int g = 4 * ((d0 >> 2) ^ l7);
        const float4 k0 = *(const float4*)&kv[l * 32 + g];
        const float4 k1 = *(const float4*)&kv[(64 + l) * 32 + g];
        const float4 k2 = *(const float4*)&kv[(128 + l) * 32 + g];
        const float4 k3 = *(const float4*)&kv[(192 + l) * 32 + g];
#pragma unroll
        for (int r = 0; r < 8; ++r) {
          const float4 q4 = *(const float4*)&qrow[(w * 8 + r) * 72 + dh * 32 + d0];
          s[r][jt * 4 + 0] = fmaf(q4.w, k0.w, fmaf(q4.z, k0.z, fmaf(q4.y, k0.y, fmaf(q4.x, k0.x, s[r][jt * 4 + 0]))));
          s[r][jt * 4 + 1] = fmaf(q4.w, k1.w, fmaf(q4.z, k1.z, fmaf(q4.y, k1.y, fmaf(q4.x, k1.x, s[r][jt * 4 + 1]))));
          s[r][jt * 4 + 2] = fmaf(q4.w, k2.w, fmaf(q4.z, k2.z, fmaf(q4.y, k2.y, fmaf(q4.x, k2.x, s[r][jt * 4 + 2]))));
          s[r][jt * 4 + 3] = fmaf(q4.w, k3.w, fmaf(q4.z, k3.z, fmaf(q4.y, k3.y, fmaf(q4.x, k3.x, s[r][jt * 4 + 3]))));
        }
      }
    }
  }
  // slot tt = jt*4+u holds col tt*64 + l  (jt*256 + u*64 + l).

  // ---- scale + softmax(dots0) -> out2 (nontemporal streaming) ----
  const size_t o2base = ((size_t)(b * 8 + h)) << 20;
#pragma unroll
  for (int r = 0; r < 8; ++r) {
#pragma unroll
    for (int tt = 0; tt < 16; ++tt) s[r][tt] *= 0.125f;
    float m = -1e30f;
#pragma unroll
    for (int tt = 0; tt < 16; ++tt) m = fmaxf(m, s[r][tt]);
    m = wmaxr(m);
    float sum = 0.0f;
#pragma unroll
    for (int tt = 0; tt < 16; ++tt) sum += __expf(s[r][tt] - m);
    sum = wsum(sum);
    const float inv = 1.0f / sum;
    float* orow = out2 + o2base + (size_t)(i0 + w * 8 + r) * 1024;
#pragma unroll
    for (int tt = 0; tt < 16; ++tt)
      __builtin_nontemporal_store(__expf(s[r][tt] - m) * inv, &orow[tt * 64 + l]);
  }

  // ---- add combined RPE bias ----
#pragma unroll
  for (int r = 0; r < 8; ++r) {
    const int xi = w * 8 + r;
#pragma unroll
    for (int tt = 0; tt < 16; ++tt) {
      const int j = tt * 64 + l;
      const int yj = j >> 5, xj = j & 31;
      s[r][tt] += bt[(31 - yj) * 63 + (xi - xj + 31)];
    }
  }

  // ---- softmax(dots) + threshold prune + renorm (e-space) ----
#pragma unroll
  for (int r = 0; r < 8; ++r) {
    float m = -1e30f, mn = 1e30f;
#pragma unroll
    for (int tt = 0; tt < 16; ++tt) { m = fmaxf(m, s[r][tt]); mn = fminf(mn, s[r][tt]); }
    m = wmaxr(m); mn = wminr(mn);
    float sum = 0.0f;
#pragma unroll
    for (int tt = 0; tt < 16; ++tt) { const float e = __expf(s[r][tt] - m); s[r][tt] = e; sum += e; }
    sum = wsum(sum);
    const float emin = __expf(mn - m);
    const float th_e = emin + tval[r] * (1.0f - emin);  // attn>th <=> e>th_e
    float deno = 0.0f;
#pragma unroll
    for (int tt = 0; tt < 16; ++tt) {
      const float a = (s[r][tt] > th_e) ? s[r][tt] : 0.0f;
      s[r][tt] = a;
      deno += a;
    }
    deno = wsum(deno);
    const float invden = 1.0f / (deno + 1e-6f * sum);
#pragma unroll
    for (int tt = 0; tt < 16; ++tt) s[r][tt] *= invden;
  }

  // ---- PV: 16 V-tiles of 64 rows, plain [64][64]; p via readlane ----
  float outv[8];
#pragma unroll
  for (int r = 0; r < 8; ++r) outv[r] = 0.0f;
  const size_t vbase = (size_t)b * 1024 * 1536 + 1024 + h * 64;
#pragma unroll
  for (int tt = 0; tt < 16; ++tt) {
    __syncthreads();
#pragma unroll
    for (int c = 0; c < 4; ++c) {  // stage 64 rows x 64 d
      const int f = (c * 256 + t) * 4;
      const int j = f >> 6, dd = f & 63;
      *(float4*)&kv[j * 64 + dd] =
          *(const float4*)&qkv[vbase + (size_t)(tt * 64 + j) * 1536 + dd];
    }
    __syncthreads();
#pragma unroll 4
    for (int jl = 0; jl < 64; ++jl) {
      const float vv = kv[jl * 64 + l];  // row broadcast, conflict-free
#pragma unroll
      for (int r = 0; r < 8; ++r) {
        const float pv = __int_as_float(
            __builtin_amdgcn_readlane(__float_as_int(s[r][tt]), jl));
        outv[r] = fmaf(pv, vv, outv[r]);
      }
    }
  }
#pragma unroll
  for (int r = 0; r < 8; ++r)
    attnout[(size_t)(b * 1024 + i0 + w * 8 + r) * 512 + h * 64 + l] = outv[r];
}

// ---------------------------------------------------------------------------
// K3: C = A @ B + bias; 64x64 tile, 4x4 microtile (r3 exact).
// ---------------------------------------------------------------------------
__global__ __launch_bounds__(256) void gemm_f32_64_bias(
    const float* __restrict__ A, const float* __restrict__ Bm,
    const float* __restrict__ bias, float* __restrict__ C,
    int M, int N, int K) {
  __shared__ float As[16][68];
  __shared__ float Bs[16][68];
  const int t = threadIdx.x;
  const int bm = blockIdx.y * 64;
  const int bn = blockIdx.x * 64;
  const int tx = t & 15;
  const int ty = t >> 4;

  float acc[4][4];
#pragma unroll
  for (int i = 0; i < 4; ++i)
#pragma unroll
    for (int j = 0; j < 4; ++j) acc[i][j] = 0.0f;

  const int amr = t >> 2;
  const int akc = (t & 3) * 4;
  const int bkr = t >> 4;
  const int bnc = (t & 15) * 4;

  for (int k0 = 0; k0 < K; k0 += 16) {
    const float4 a0 = *(const float4*)&A[(size_t)(bm + amr) * K + k0 + akc];
    const float4 b0 = *(const float4*)&Bm[(size_t)(k0 + bkr) * N + bn + bnc];
    __syncthreads();
    As[akc + 0][amr] = a0.x; As[akc + 1][amr] = a0.y;
    As[akc + 2][amr] = a0.z; As[akc + 3][amr] = a0.w;
    *(float4*)&Bs[bkr][bnc] = b0;
    __syncthreads();
#pragma unroll
    for (int kk = 0; kk < 16; ++kk) {
      const float4 av = *(const float4*)&As[kk][ty * 4];
      const float4 bv = *(const float4*)&Bs[kk][tx * 4];
      const float aa[4] = {av.x, av.y, av.z, av.w};
      const float bb[4] = {bv.x, bv.y, bv.z, bv.w};
#pragma unroll
      for (int i = 0; i < 4; ++i)
#pragma unroll
        for (int j = 0; j < 4; ++j) acc[i][j] += aa[i] * bb[j];
    }
  }

  const float4 bi = *(const float4*)&bias[bn + tx * 4];
#pragma unroll
  for (int i = 0; i < 4; ++i) {
    float4 o;
    o.x = acc[i][0] + bi.x; o.y = acc[i][1] + bi.y;
    o.z = acc[i][2] + bi.z; o.w = acc[i][3] + bi.w;
    *(float4*)&C[(size_t)(bm + ty * 4 + i) * N + bn + tx * 4] = o;
  }
}

// ---------------------------------------------------------------------------
extern "C" void kernel_launch(void* const* d_in, const int* in_sizes, int n_in,
                              void* d_out, int out_size, void* d_ws, size_t ws_size,
                              hipStream_t stream) {
  const float* x        = (const float*)d_in[0];  // [4,1024,512]
  const float* prob     = (const float*)d_in[1];  // [4,1024]
  const float* w_qkv    = (const float*)d_in[2];  // [512,1536]
  const float* rpb      = (const float*)d_in[3];  // [3969,8]
  const float* headsita = (const float*)d_in[4];  // [8]
  const float* w_thresh = (const float*)d_in[5];  // [64]
  const float* w_out    = (const float*)d_in[6];  // [512,512]
  const float* b_out    = (const float*)d_in[7];  // [512]
  // d_in[8] = rpi, d_in[9] = dis : recomputed analytically.

  float* out  = (float*)d_out;                    // [4,1024,512]
  float* out2 = out + (size_t)4 * 1024 * 512;     // [4,8,1024,1024]

  float* qkv     = (float*)d_ws;                      // 6.29M floats
  float* attnout = qkv + (size_t)4 * 1024 * 1536;     // 2.1M floats
  float* btab    = attnout + (size_t)4 * 1024 * 512;  // 8*3969 floats

  // 0) combined bias table
  build_btab<<<dim3(16, 8), 256, 0, stream>>>(rpb, headsita, btab);

  // 1) QKV projection: [4096,512] @ [512,1536]
  gemm_f32_128<<<dim3(1536 / 128, 4096 / 128), 256, 0, stream>>>(
      x, w_qkv, qkv, 4096, 1536, 512);

  // 2) fused attention
  attn_fused<<<dim3(32, 32), 256, 0, stream>>>(
      qkv, prob, btab, w_thresh, out2, attnout);

  // 3) output projection + bias: [4096,512] @ [512,512]
  gemm_f32_64_bias<<<dim3(512 / 64, 4096 / 64), 256, 0, stream>>>(
      attnout, w_out, b_out, out, 4096, 512, 512);
}